// Round 1
// baseline (72.668 us; speedup 1.0000x reference)
//
#include <hip/hip_runtime.h>

// EncodingLayer: B=16, N=1024 (32x32), D=128, K=32
//   A = softmax_k( scale_k * ||x_n - c_k||^2 )
//   E[b,k,d] = sum_n A[b,n,k]*x[b,n,d] - (sum_n A[b,n,k]) * c[k,d]
//
// R8: single kernel + fp32 atomics (replaces R6's ws+reduce pair).
//   - 512 blocks = 16 batches x 32 splits of 32 pixels (2 blocks/CU).
//   - Phase 1a: S = X*C^T via v_mfma_f32_32x32x16_bf16 (8 K-steps, D=128).
//   - Phase 1b: softmax in C-layout regs -> A^T bf16 + a_sum.
//   - Phase 2:  E_part = A^T * X via 2 MFMAs/wave (wave = d-quarter).
//   - Epilogue: fold -a_sum*c, then global_atomic_add_f32 directly into out
//     (pre-zeroed by a 262 KB hipMemsetAsync in the same graph).
//   Removes: 4 MB bf16 ws write + 4 MB ws read + enc_reduce launch.
//   (R7 flag-poll fusion regressed +24us -- this is fire-and-forget, no
//   polling, no cross-XCD data reads; atomics resolve at L2/coherence point.)

typedef __attribute__((ext_vector_type(8))) short bf16x8;   // 8 bf16 = 4 VGPRs
typedef __attribute__((ext_vector_type(16))) float f32x16;  // MFMA 32x32 C/D

constexpr int XBS = 136;  // bf16 X/C row stride (shorts): 272 B, 16B-aligned
constexpr int AST = 40;   // A^T row stride (shorts): 80 B, 16B-aligned

__device__ __forceinline__ unsigned short f2bf(float f) {
    unsigned u = __float_as_uint(f);
    u += 0x7fffu + ((u >> 16) & 1u);          // round-to-nearest-even
    return (unsigned short)(u >> 16);
}
__device__ __forceinline__ float bf2f(unsigned short h) {
    return __uint_as_float((unsigned)h << 16);
}

__global__ __launch_bounds__(256)
void enc_partial(const float* __restrict__ x, const float* __restrict__ cw,
                 const float* __restrict__ scale, float* __restrict__ out)
{
    __shared__ unsigned short xb_s[32 * XBS];  // 8.5 KB bf16 X
    __shared__ unsigned short cb_s[32 * XBS];  // 8.5 KB bf16 C
    __shared__ unsigned short At_s[32 * AST];  // 2.5 KB bf16 A^T [k][n]
    __shared__ float x2_s[32], c2_s[32];
    __shared__ float asum_s[4 * 32];           // per-wave a_sum partials
    __shared__ float asumf_s[32];              // final a_sum[k]

    const int tid = threadIdx.x;
    const int b   = blockIdx.x >> 5;
    const int s   = blockIdx.x & 31;
    const int lc  = tid & 31;        // lane&31
    const int lh  = (tid >> 5) & 1;  // lane>>5 within wave
    const int w   = tid >> 6;        // wave id

    const float4* xg4 = (const float4*)(x + (size_t)(b * 1024 + s * 32) * 128);
    const float4* cg4 = (const float4*)cw;

    // ---- staging: bf16 tiles + row norms via half-wave shuffle reduce ----
#pragma unroll
    for (int i = 0; i < 4; ++i) {
        const int f   = tid + 256 * i;
        const int row = 8 * i + (tid >> 5);
        const int col = tid & 31;
        float4 vx = xg4[f];
        float4 vc = cg4[f];
        short4 hx = { (short)f2bf(vx.x), (short)f2bf(vx.y),
                      (short)f2bf(vx.z), (short)f2bf(vx.w) };
        short4 hc = { (short)f2bf(vc.x), (short)f2bf(vc.y),
                      (short)f2bf(vc.z), (short)f2bf(vc.w) };
        *(short4*)&xb_s[row * XBS + col * 4] = hx;
        *(short4*)&cb_s[row * XBS + col * 4] = hc;
        float sx = vx.x * vx.x + vx.y * vx.y + vx.z * vx.z + vx.w * vx.w;
        float sc = vc.x * vc.x + vc.y * vc.y + vc.z * vc.z + vc.w * vc.w;
#pragma unroll
        for (int m = 16; m >= 1; m >>= 1) {
            sx += __shfl_xor(sx, m);
            sc += __shfl_xor(sc, m);
        }
        if (col == 0) { x2_s[row] = sx; c2_s[row] = sc; }
    }
    __syncthreads();

    // ---- phase 1a: S = X*C^T via MFMA (each wave computes full 32x32) ----
    f32x16 acc;
#pragma unroll
    for (int i = 0; i < 16; ++i) acc[i] = 0.f;
#pragma unroll
    for (int t = 0; t < 8; ++t) {
        bf16x8 af  = *(const bf16x8*)&xb_s[lc * XBS + t * 16 + lh * 8];
        bf16x8 bfr = *(const bf16x8*)&cb_s[lc * XBS + t * 16 + lh * 8];
        acc = __builtin_amdgcn_mfma_f32_32x32x16_bf16(af, bfr, acc, 0, 0, 0);
    }

    // ---- phase 1b: softmax over k; write A^T bf16 + a_sum partials ----
    // C-layout: col k = lc, row n = (reg&3) + 8*(reg>>2) + 4*lh; wave w uses
    // regs 4w+q -> rows n = q + 8w + 4lh (the 4 waves cover all 32 rows).
    {
        const float sck = scale[lc];
        const float c2k = c2_s[lc];
        const float4 x2v = *(const float4*)&x2_s[8 * w + 4 * lh];
        float sl[4] = {
            sck * (x2v.x - 2.f * acc[4 * w + 0] + c2k),
            sck * (x2v.y - 2.f * acc[4 * w + 1] + c2k),
            sck * (x2v.z - 2.f * acc[4 * w + 2] + c2k),
            sck * (x2v.w - 2.f * acc[4 * w + 3] + c2k) };
        float a[4];
#pragma unroll
        for (int q = 0; q < 4; ++q) {
            float m = sl[q];
#pragma unroll
            for (int msk = 16; msk >= 1; msk >>= 1) m = fmaxf(m, __shfl_xor(m, msk));
            float e = __expf(sl[q] - m);
            float den = e;
#pragma unroll
            for (int msk = 16; msk >= 1; msk >>= 1) den += __shfl_xor(den, msk);
            a[q] = e / den;
        }
        // A^T[k=lc][n = 8w+4lh + q], q=0..3 consecutive -> one packed short4
        short4 ha = { (short)f2bf(a[0]), (short)f2bf(a[1]),
                      (short)f2bf(a[2]), (short)f2bf(a[3]) };
        *(short4*)&At_s[lc * AST + 8 * w + 4 * lh] = ha;
        float ap = (a[0] + a[1]) + (a[2] + a[3]);
        ap += __shfl_xor(ap, 32);          // combine lh halves -> 8-row partial
        if (lh == 0) asum_s[w * 32 + lc] = ap;
    }
    __syncthreads();

    // finalize a_sum[k] (threads 0..31) while others start phase-2 MFMA
    if (tid < 32)
        asumf_s[tid] = (asum_s[tid] + asum_s[32 + tid]) +
                       (asum_s[64 + tid] + asum_s[96 + tid]);

    // ---- phase 2: E_part = A^T * X via MFMA; wave w = d-quarter ----
    // A-frag: lane holds A^T[kk=lc][n = t*16+lh*8+j] (b128 from At_s).
    // B-frag: lane holds X[n = t*16+lh*8+j][dd = 32w+lc] (u16 column reads).
    f32x16 e;
#pragma unroll
    for (int i = 0; i < 16; ++i) e[i] = 0.f;
#pragma unroll
    for (int t = 0; t < 2; ++t) {
        bf16x8 af = *(const bf16x8*)&At_s[lc * AST + t * 16 + lh * 8];
        const int nb = t * 16 + lh * 8;
        bf16x8 bfr;
#pragma unroll
        for (int j = 0; j < 8; ++j)
            bfr[j] = (short)xb_s[(nb + j) * XBS + w * 32 + lc];
        e = __builtin_amdgcn_mfma_f32_32x32x16_bf16(af, bfr, e, 0, 0, 0);
    }
    __syncthreads();   // asumf_s ready for everyone

    // ---- epilogue: fold -a_sum*c, atomic-accumulate fp32 into out ----
    // 16 global_atomic_add_f32 per lane; per r, half-wave covers 128
    // consecutive bytes of one k-row. 2M atomics over 4096 cache lines.
    {
        float* ob = out + (size_t)b * 4096;
        const int dd = w * 32 + lc;
#pragma unroll
        for (int r = 0; r < 16; ++r) {
            const int kk = (r & 3) + 8 * (r >> 2) + 4 * lh;
            float v = e[r] - asumf_s[kk] * bf2f(cb_s[kk * XBS + dd]);
            unsafeAtomicAdd(&ob[kk * 128 + dd], v);   // global_atomic_add_f32
        }
    }
}

extern "C" void kernel_launch(void* const* d_in, const int* in_sizes, int n_in,
                              void* d_out, int out_size, void* d_ws, size_t ws_size,
                              hipStream_t stream)
{
    const float* x     = (const float*)d_in[0];  // [16,32,32,128]
    const float* cw    = (const float*)d_in[1];  // [32,128]
    const float* scale = (const float*)d_in[2];  // [32]
    float* out = (float*)d_out;                  // [16,32,128] fp32

    // pre-zero the 262 KB output; graph-capturable stream op
    hipMemsetAsync(out, 0, (size_t)16 * 32 * 128 * sizeof(float), stream);
    enc_partial<<<512, 256, 0, stream>>>(x, cw, scale, out);
}

// Round 2
// 67.170 us; speedup vs baseline: 1.0819x; 1.0819x over previous
//
#include <hip/hip_runtime.h>

// EncodingLayer: B=16, N=1024 (32x32), D=128, K=32
//   A = softmax_k( scale_k * ||x_n - c_k||^2 )
//   E[b,k,d] = sum_n A[b,n,k]*x[b,n,d] - (sum_n A[b,n,k]) * c[k,d]
//
// R9: revert to the R6 two-kernel structure (best measured: 68.1us) and
// rebuild enc_reduce for occupancy.
//   History: R7 flag-poll fusion +24us (cross-XCD poll + acquire-inval);
//            R8 atomic fusion +4.6us (32 writers/address serialize at the
//            coherence point; memset dispatch ate the boundary saving).
//   => the cross-split combine is cheapest as a separate kernel whose reads
//      hit L3 (k1's ws writes are flushed at kernel end).
// k1: 512 blocks = 16 batches x 32 splits of 32 pixels (2 blocks/CU).
//     Phase 1a: S = X*C^T via v_mfma_f32_32x32x16_bf16 (8 K-steps, D=128).
//     Phase 1b: softmax in C-layout regs -> A^T bf16 + a_sum.
//     Phase 2:  E_part = A^T * X via 2 MFMAs/wave (wave = d-quarter).
//     Epilogue: fold -a_sum*c, store bf16 partials to ws.
// k2 (NEW): 256 blocks x 256 threads (4 waves/CU, was 1 wave/CU).
//     Each wave sums 8 of the 32 slices (8 independent loads in flight),
//     then 2-level LDS combine; wave 0 stores float4.

typedef __attribute__((ext_vector_type(8))) short bf16x8;   // 8 bf16 = 4 VGPRs
typedef __attribute__((ext_vector_type(16))) float f32x16;  // MFMA 32x32 C/D

constexpr int XBS = 136;  // bf16 X/C row stride (shorts): 272 B, 16B-aligned
constexpr int AST = 40;   // A^T row stride (shorts): 80 B, 16B-aligned

__device__ __forceinline__ unsigned short f2bf(float f) {
    unsigned u = __float_as_uint(f);
    u += 0x7fffu + ((u >> 16) & 1u);          // round-to-nearest-even
    return (unsigned short)(u >> 16);
}
__device__ __forceinline__ float bf2f(unsigned short h) {
    return __uint_as_float((unsigned)h << 16);
}

__global__ __launch_bounds__(256)
void enc_partial(const float* __restrict__ x, const float* __restrict__ cw,
                 const float* __restrict__ scale, unsigned short* __restrict__ ws)
{
    __shared__ unsigned short xb_s[32 * XBS];  // 8.5 KB bf16 X
    __shared__ unsigned short cb_s[32 * XBS];  // 8.5 KB bf16 C
    __shared__ unsigned short At_s[32 * AST];  // 2.5 KB bf16 A^T [k][n]
    __shared__ float x2_s[32], c2_s[32];
    __shared__ float asum_s[4 * 32];           // per-wave a_sum partials
    __shared__ float asumf_s[32];              // final a_sum[k]

    const int tid = threadIdx.x;
    const int b   = blockIdx.x >> 5;
    const int s   = blockIdx.x & 31;
    const int lc  = tid & 31;        // lane&31
    const int lh  = (tid >> 5) & 1;  // lane>>5 within wave
    const int w   = tid >> 6;        // wave id

    const float4* xg4 = (const float4*)(x + (size_t)(b * 1024 + s * 32) * 128);
    const float4* cg4 = (const float4*)cw;

    // ---- staging: bf16 tiles + row norms via half-wave shuffle reduce ----
#pragma unroll
    for (int i = 0; i < 4; ++i) {
        const int f   = tid + 256 * i;
        const int row = 8 * i + (tid >> 5);
        const int col = tid & 31;
        float4 vx = xg4[f];
        float4 vc = cg4[f];
        short4 hx = { (short)f2bf(vx.x), (short)f2bf(vx.y),
                      (short)f2bf(vx.z), (short)f2bf(vx.w) };
        short4 hc = { (short)f2bf(vc.x), (short)f2bf(vc.y),
                      (short)f2bf(vc.z), (short)f2bf(vc.w) };
        *(short4*)&xb_s[row * XBS + col * 4] = hx;
        *(short4*)&cb_s[row * XBS + col * 4] = hc;
        float sx = vx.x * vx.x + vx.y * vx.y + vx.z * vx.z + vx.w * vx.w;
        float sc = vc.x * vc.x + vc.y * vc.y + vc.z * vc.z + vc.w * vc.w;
#pragma unroll
        for (int m = 16; m >= 1; m >>= 1) {
            sx += __shfl_xor(sx, m);
            sc += __shfl_xor(sc, m);
        }
        if (col == 0) { x2_s[row] = sx; c2_s[row] = sc; }
    }
    __syncthreads();

    // ---- phase 1a: S = X*C^T via MFMA (each wave computes full 32x32) ----
    f32x16 acc;
#pragma unroll
    for (int i = 0; i < 16; ++i) acc[i] = 0.f;
#pragma unroll
    for (int t = 0; t < 8; ++t) {
        bf16x8 af  = *(const bf16x8*)&xb_s[lc * XBS + t * 16 + lh * 8];
        bf16x8 bfr = *(const bf16x8*)&cb_s[lc * XBS + t * 16 + lh * 8];
        acc = __builtin_amdgcn_mfma_f32_32x32x16_bf16(af, bfr, acc, 0, 0, 0);
    }

    // ---- phase 1b: softmax over k; write A^T bf16 + a_sum partials ----
    // C-layout: col k = lc, row n = (reg&3) + 8*(reg>>2) + 4*lh; wave w uses
    // regs 4w+q -> rows n = q + 8w + 4lh (the 4 waves cover all 32 rows).
    {
        const float sck = scale[lc];
        const float c2k = c2_s[lc];
        const float4 x2v = *(const float4*)&x2_s[8 * w + 4 * lh];
        float sl[4] = {
            sck * (x2v.x - 2.f * acc[4 * w + 0] + c2k),
            sck * (x2v.y - 2.f * acc[4 * w + 1] + c2k),
            sck * (x2v.z - 2.f * acc[4 * w + 2] + c2k),
            sck * (x2v.w - 2.f * acc[4 * w + 3] + c2k) };
        float a[4];
#pragma unroll
        for (int q = 0; q < 4; ++q) {
            float m = sl[q];
#pragma unroll
            for (int msk = 16; msk >= 1; msk >>= 1) m = fmaxf(m, __shfl_xor(m, msk));
            float e = __expf(sl[q] - m);
            float den = e;
#pragma unroll
            for (int msk = 16; msk >= 1; msk >>= 1) den += __shfl_xor(den, msk);
            a[q] = e / den;
        }
        // A^T[k=lc][n = 8w+4lh + q], q=0..3 consecutive -> one packed short4
        short4 ha = { (short)f2bf(a[0]), (short)f2bf(a[1]),
                      (short)f2bf(a[2]), (short)f2bf(a[3]) };
        *(short4*)&At_s[lc * AST + 8 * w + 4 * lh] = ha;
        float ap = (a[0] + a[1]) + (a[2] + a[3]);
        ap += __shfl_xor(ap, 32);          // combine lh halves -> 8-row partial
        if (lh == 0) asum_s[w * 32 + lc] = ap;
    }
    __syncthreads();

    // finalize a_sum[k] (threads 0..31) while others start phase-2 MFMA
    if (tid < 32)
        asumf_s[tid] = (asum_s[tid] + asum_s[32 + tid]) +
                       (asum_s[64 + tid] + asum_s[96 + tid]);

    // ---- phase 2: E_part = A^T * X via MFMA; wave w = d-quarter ----
    // A-frag: lane holds A^T[kk=lc][n = t*16+lh*8+j] (b128 from At_s).
    // B-frag: lane holds X[n = t*16+lh*8+j][dd = 32w+lc] (u16 column reads).
    f32x16 e;
#pragma unroll
    for (int i = 0; i < 16; ++i) e[i] = 0.f;
#pragma unroll
    for (int t = 0; t < 2; ++t) {
        bf16x8 af = *(const bf16x8*)&At_s[lc * AST + t * 16 + lh * 8];
        const int nb = t * 16 + lh * 8;
        bf16x8 bfr;
#pragma unroll
        for (int j = 0; j < 8; ++j)
            bfr[j] = (short)xb_s[(nb + j) * XBS + w * 32 + lc];
        e = __builtin_amdgcn_mfma_f32_32x32x16_bf16(af, bfr, e, 0, 0, 0);
    }
    __syncthreads();   // asumf_s ready for everyone

    // ---- epilogue: fold -a_sum*c (c from LDS), store bf16 partial slice ----
    {
        unsigned short* wb = ws + (size_t)(b * 32 + s) * 4096;
        const int dd = w * 32 + lc;
#pragma unroll
        for (int r = 0; r < 16; ++r) {
            const int kk = (r & 3) + 8 * (r >> 2) + 4 * lh;
            float v = e[r] - asumf_s[kk] * bf2f(cb_s[kk * XBS + dd]);
            wb[kk * 128 + dd] = f2bf(v);   // coalesced 64B/half-wave
        }
    }
}

// Sum the 32 bf16 slices per batch: out[b][j] = sum_s ws[(b*32+s)*4096 + j]
// R9: 256 blocks x 256 threads (4 waves/CU; the old 64-thread version was
// 1 wave/CU with 32 serial-ish loads -- pure latency exposure).
// Block handles 64 quads (256 floats) of one batch; wave sg sums slices
// [8*sg, 8*sg+8), all 8 loads independent and in flight together.
__global__ __launch_bounds__(256)
void enc_reduce(const unsigned short* __restrict__ ws, float* __restrict__ out)
{
    __shared__ float red_s[3][256];      // sg=1..3 partials (64 quads x 4)

    const int tid  = threadIdx.x;
    const int lane = tid & 63;
    const int sg   = tid >> 6;                   // 0..3: slice group
    const int b    = blockIdx.x >> 4;            // 16 blocks per batch
    const int q    = (blockIdx.x & 15) * 64 + lane;  // quad 0..1023
    const unsigned short* base = ws + (size_t)b * 131072 + q * 4;

    float4 a0 = {0,0,0,0}, a1 = {0,0,0,0};
#pragma unroll
    for (int s = 0; s < 8; s += 2) {
        ushort4 v0 = *(const ushort4*)&base[(sg * 8 + s + 0) * 4096];
        ushort4 v1 = *(const ushort4*)&base[(sg * 8 + s + 1) * 4096];
        a0.x += bf2f(v0.x); a0.y += bf2f(v0.y); a0.z += bf2f(v0.z); a0.w += bf2f(v0.w);
        a1.x += bf2f(v1.x); a1.y += bf2f(v1.y); a1.z += bf2f(v1.z); a1.w += bf2f(v1.w);
    }
    float4 a;
    a.x = a0.x + a1.x; a.y = a0.y + a1.y; a.z = a0.z + a1.z; a.w = a0.w + a1.w;

    if (sg) *(float4*)&red_s[sg - 1][lane * 4] = a;
    __syncthreads();
    if (sg == 0) {
        float4 r0 = *(const float4*)&red_s[0][lane * 4];
        float4 r1 = *(const float4*)&red_s[1][lane * 4];
        float4 r2 = *(const float4*)&red_s[2][lane * 4];
        float4 r;
        r.x = (a.x + r0.x) + (r1.x + r2.x);
        r.y = (a.y + r0.y) + (r1.y + r2.y);
        r.z = (a.z + r0.z) + (r1.z + r2.z);
        r.w = (a.w + r0.w) + (r1.w + r2.w);
        *(float4*)&out[(size_t)b * 4096 + q * 4] = r;
    }
}

extern "C" void kernel_launch(void* const* d_in, const int* in_sizes, int n_in,
                              void* d_out, int out_size, void* d_ws, size_t ws_size,
                              hipStream_t stream)
{
    const float* x     = (const float*)d_in[0];  // [16,32,32,128]
    const float* cw    = (const float*)d_in[1];  // [32,128]
    const float* scale = (const float*)d_in[2];  // [32]
    float* out = (float*)d_out;                  // [16,32,128]
    unsigned short* ws = (unsigned short*)d_ws;  // 4 MB bf16 partials

    enc_partial<<<512, 256, 0, stream>>>(x, cw, scale, ws);
    enc_reduce<<<256, 256, 0, stream>>>(ws, out);
}